// Round 7
// baseline (694.923 us; speedup 1.0000x reference)
//
#include <hip/hip_runtime.h>
#include <hip/hip_bf16.h>

#define N 1024
#define D 128
#define SB 32          // steps per superstep (gi chunk staged in LDS)
#define NSB (N / SB)

typedef __hip_bfloat16 bf16;
typedef __attribute__((ext_vector_type(2))) _Float16 f16x2;
typedef __attribute__((ext_vector_type(4))) float fx4;
typedef __attribute__((ext_vector_type(8))) unsigned short u16x8;

__device__ __forceinline__ float b2f(bf16 x) { return __bfloat162float(x); }
__device__ __forceinline__ unsigned short f2bf_bits(float x) {
    bf16 b = __float2bfloat16(x);
    return *reinterpret_cast<unsigned short*>(&b);
}
__device__ __forceinline__ float bfbits2f(unsigned short u) {
    return __uint_as_float(((unsigned int)u) << 16);
}
__device__ __forceinline__ float fastrcp(float x) { return __builtin_amdgcn_rcpf(x); }

__device__ __forceinline__ float fast_tanh(float x) {
    float e = __expf(2.f * x);
    return 1.f - 2.f * fastrcp(e + 1.f);
}
__device__ __forceinline__ float fast_sigmoid(float x) {
    return fastrcp(1.f + __expf(-x));
}

__device__ __forceinline__ float fdot2(f16x2 a, f16x2 b, float c) {
#if __has_builtin(__builtin_amdgcn_fdot2)
    return __builtin_amdgcn_fdot2(a, b, c, false);
#else
    return fmaf((float)a[0], (float)b[0], fmaf((float)a[1], (float)b[1], c));
#endif
}

// async 16B global->LDS (lds base wave-uniform; HW scatters lane i at base+i*16)
__device__ __forceinline__ void async_copy16(const float* g, void* l) {
    __builtin_amdgcn_global_load_lds((const __attribute__((address_space(1))) void*)g,
                                     (__attribute__((address_space(3))) void*)l, 16, 0, 0);
}

// ---------------- K0a: dtype sniff ----------------
__global__ void sniff_kernel(const unsigned short* __restrict__ xu, int* __restrict__ flag) {
    int l = threadIdx.x;  // 64 threads
    int cnt = 0;
#pragma unroll
    for (int k = 0; k < 8; ++k) {
        unsigned short u = xu[2 * (l * 8 + k)];
        int e = (u >> 7) & 0xFF;
        cnt += (e >= 96 && e <= 144) ? 1 : 0;
    }
    for (int off = 32; off > 0; off >>= 1) cnt += __shfl_down(cnt, off);
    if (l == 0) *flag = (cnt > 400) ? 1 : 0;
}

// ---------------- K0b: convert all inputs to fp32 in ws ----------------
struct ConvArgs {
    const void* p[8];
    float* o[8];
    int n[8];
};
__global__ void convert_kernel(ConvArgs A, const int* __restrict__ flag) {
    int seg = blockIdx.y;
    int n = A.n[seg];
    int isbf = *flag;
    const void* p = A.p[seg];
    float* o = A.o[seg];
    for (int i = blockIdx.x * blockDim.x + threadIdx.x; i < n; i += gridDim.x * blockDim.x) {
        float v = isbf ? b2f(((const bf16*)p)[i]) : ((const float*)p)[i];
        o[i] = v;
    }
}

// ---------------- K0c: w_ihT[c][o] = w_ih[o][c] ----------------
__global__ void transpose_wih(const float* __restrict__ wih, float* __restrict__ wihT) {
    int id = blockIdx.x * 256 + threadIdx.x;   // 98304 total
    int c = id / 384;
    int o = id - c * 384;
    wihT[id] = wih[o * 256 + c];
}

// ---------------- K1: q = X@Wq^T, kT = (X@Wk^T)^T ----------------
__global__ void qk_kernel(const float* __restrict__ X, const float* __restrict__ Wq,
                          const float* __restrict__ Wk,
                          float* __restrict__ q, float* __restrict__ kT) {
    int i = blockIdx.x & (N - 1);
    bool is_k = blockIdx.x >= N;
    int d = threadIdx.x;  // 0..127
    const float* W = is_k ? Wk : Wq;
    float acc = 0.f;
#pragma unroll 8
    for (int c = 0; c < D; ++c)
        acc += X[i * D + c] * W[d * D + c];
    if (is_k) kT[d * N + i] = acc;
    else      q[i * D + d] = acc;
}

// ---------------- K2: fused scores+softmax+att+gi per row i ----------------
__global__ void __launch_bounds__(256) attn_kernel(const float* __restrict__ q,
                                                   const float* __restrict__ kT,
                                                   const float* __restrict__ v,
                                                   const float* __restrict__ X,
                                                   const float* __restrict__ wihT,
                                                   const float* __restrict__ b_ih,
                                                   float* __restrict__ gi) {
    int i = blockIdx.x;
    __shared__ float qs[D], vs[D], xr[D], al[D];
    __shared__ float wrow[N];
    __shared__ float red[256];
    int t = threadIdx.x;
    if (t < D) { qs[t] = q[i * D + t]; vs[t] = v[t]; xr[t] = X[i * D + t]; }
    __syncthreads();

    float sj[4];
    int cnt = 0;
    float m = -1e30f;
    for (int j = i + t; j < N; j += 256) {
        float s = 0.f;
#pragma unroll 8
        for (int d = 0; d < D; ++d) s += vs[d] * fast_tanh(qs[d] + kT[d * N + j]);
        sj[cnt++] = s;
        m = fmaxf(m, s);
    }
    red[t] = m;
    __syncthreads();
    for (int st = 128; st > 0; st >>= 1) {
        if (t < st) red[t] = fmaxf(red[t], red[t + st]);
        __syncthreads();
    }
    m = red[0];
    __syncthreads();
    float lsum = 0.f;
    {
        int it = 0;
        for (int j = i + t; j < N; j += 256, ++it) {
            float p = __expf(sj[it] - m);
            wrow[j] = p;
            lsum += p;
        }
    }
    red[t] = lsum;
    __syncthreads();
    for (int st = 128; st > 0; st >>= 1) {
        if (t < st) red[t] += red[t + st];
        __syncthreads();
    }
    float inv = fastrcp(red[0]);
    __syncthreads();

    int d = t & 127, half = t >> 7;
    float acc = 0.f;
    for (int j = i + half; j < N; j += 2) acc += wrow[j] * X[j * D + d];
    if (half) red[d] = acc;
    __syncthreads();
    if (!half) al[d] = (acc + red[d]) * inv;
    __syncthreads();

    for (int o = t; o < 3 * D; o += 256) {
        float a2 = b_ih[o];
        const float* wt = wihT + o;
#pragma unroll 8
        for (int c = 0; c < D; ++c) a2 += xr[c] * wt[c * 384];
#pragma unroll 8
        for (int c = 0; c < D; ++c) a2 += al[c] * wt[(D + c) * 384];
        gi[i * 3 * D + o] = a2;
    }
}

// ---------------- K3: sequential GRU via v_dot2_f32_f16, 4 waves ----------------
// Thread t: dim d = t>>1, k-half = t&1. Weights rows {d, d+128, d+256} x 64-k-half
// resident as 96 f16x2 VGPRs. Per step: 8 ds_read_b128 of h (f16; 2-address
// broadcast pattern = conflict-free), 96 fdot2 in 6 independent chains, 3
// shfl_xor(1) pair-combines, gates per-thread (no selects), h -> f16 ping-pong
// (recurrence) + bf16 obuf (output), one lgkm-only barrier per step.
// MFMA pipe no longer used: its 384 cyc/step floor was the R6 bottleneck.
__global__ void __launch_bounds__(256, 1) gru_kernel(const float* __restrict__ gi,
                                                     const float* __restrict__ w_hh,
                                                     const float* __restrict__ b_hh,
                                                     void* __restrict__ out,
                                                     const int* __restrict__ flag) {
    __shared__ float gi_lds[2][SB][3 * D];     // 2 x 48 KB
    __shared__ f16x2 hcur[2][D / 2];           // h ping-pong, f16, 256 B each
    __shared__ unsigned short obuf[SB][D];     // bf16 output staging, 8 KB
    int t = threadIdx.x;
    int d = t >> 1;
    int half = t & 1;
    int isbf = *flag;

    // --- weights: rows d, d+128, d+256, k in [64*half, 64*half+64), as f16 pairs ---
    f16x2 wr[32], wz[32], wn[32];
    {
        const float* wb = w_hh + 64 * half;
#pragma unroll
        for (int j = 0; j < 32; ++j) {
            wr[j] = f16x2{(_Float16)wb[d * D + 2 * j], (_Float16)wb[d * D + 2 * j + 1]};
            wz[j] = f16x2{(_Float16)wb[(d + D) * D + 2 * j], (_Float16)wb[(d + D) * D + 2 * j + 1]};
            wn[j] = f16x2{(_Float16)wb[(d + 2 * D) * D + 2 * j], (_Float16)wb[(d + 2 * D) * D + 2 * j + 1]};
        }
    }
    float br = b_hh[d], bz = b_hh[D + d], bn = b_hh[2 * D + d];
    float h = 0.f;

    int fr = t >> 3;            // obuf flush: row fr, 16 cols at fc
    int fc = (t & 7) * 16;

    // prefetch superstep 0
    {
        for (int mm = 0; mm < 12; ++mm) {
            int off = ((t >> 6) * 12 + mm) * 256;
            async_copy16(gi + off + ((t & 63) << 2), (char*)&gi_lds[0][0][0] + off * 4);
        }
    }

    for (int sb = 0; sb < NSB; ++sb) {
        int cb = sb & 1;
        if (sb == 0) {
            if (t < 64) ((int*)&hcur[0][0])[t] = 0;
        } else {
            // flush previous superstep's obuf (rows (sb-1)*SB + 0..31)
            u16x8 h0 = *(const u16x8*)&obuf[fr][fc];
            u16x8 h1 = *(const u16x8*)&obuf[fr][fc + 8];
            int orow = (sb - 1) * SB + fr;
            if (isbf) {
                *(u16x8*)((unsigned short*)out + orow * D + fc) = h0;
                *(u16x8*)((unsigned short*)out + orow * D + fc + 8) = h1;
            } else {
                float* op = (float*)out + orow * D + fc;
                fx4 f0, f1, f2, f3;
#pragma unroll
                for (int j = 0; j < 4; ++j) {
                    f0[j] = bfbits2f(h0[j]);     f1[j] = bfbits2f(h0[4 + j]);
                    f2[j] = bfbits2f(h1[j]);     f3[j] = bfbits2f(h1[4 + j]);
                }
                *(fx4*)op = f0; *(fx4*)(op + 4) = f1;
                *(fx4*)(op + 8) = f2; *(fx4*)(op + 12) = f3;
            }
        }
        // boundary: drain prefetch + flush stores; separates obuf reads from rewrites
        asm volatile("s_waitcnt vmcnt(0) lgkmcnt(0)\ns_barrier" ::: "memory");

        if (sb + 1 < NSB) {
            const float* src = gi + (size_t)(sb + 1) * SB * 3 * D;
            for (int mm = 0; mm < 12; ++mm) {
                int off = ((t >> 6) * 12 + mm) * 256;
                async_copy16(src + off + ((t & 63) << 2), (char*)&gi_lds[cb ^ 1][0][0] + off * 4);
            }
        }

        const float* gp = &gi_lds[cb][0][0] + d;   // step stride 3*D floats

        for (int s = 0; s < SB; ++s) {
            int pp = s & 1;   // global-step parity (SB even)
            // h chunk: 64 f16 = 128 B as 8 b128 reads (union keeps it in regs)
            union { fx4 v4[8]; f16x2 h2[32]; } hu;
            {
                const fx4* hp4 = (const fx4*)&hcur[pp][half * 32];
#pragma unroll
                for (int j = 0; j < 8; ++j) hu.v4[j] = hp4[j];
            }
            float gr = gp[0];
            float gz = gp[D];
            float gn = gp[2 * D];

            float r0 = 0.f, r1 = 0.f, z0 = 0.f, z1 = 0.f, n0 = 0.f, n1 = 0.f;
#pragma unroll
            for (int j = 0; j < 16; ++j) {
                r0 = fdot2(wr[j], hu.h2[j], r0);
                r1 = fdot2(wr[j + 16], hu.h2[j + 16], r1);
                z0 = fdot2(wz[j], hu.h2[j], z0);
                z1 = fdot2(wz[j + 16], hu.h2[j + 16], z1);
                n0 = fdot2(wn[j], hu.h2[j], n0);
                n1 = fdot2(wn[j + 16], hu.h2[j + 16], n1);
            }
            float sr = r0 + r1, sz = z0 + z1, sn = n0 + n1;
            sr += __shfl_xor(sr, 1);
            sz += __shfl_xor(sz, 1);
            sn += __shfl_xor(sn, 1);

            float rr = fast_sigmoid(gr + sr + br);
            float zz = fast_sigmoid(gz + sz + bz);
            float nst = fast_tanh(gn + rr * (sn + bn));
            h = (1.f - zz) * nst + zz * h;

            if (!half) {
                ((_Float16*)&hcur[pp ^ 1][0])[d] = (_Float16)h;
                obuf[s][d] = f2bf_bits(h);
            }
            gp += 3 * D;
            asm volatile("s_waitcnt lgkmcnt(0)\ns_barrier" ::: "memory");
        }
    }
    // final flush (last superstep's obuf)
    {
        u16x8 h0 = *(const u16x8*)&obuf[fr][fc];
        u16x8 h1 = *(const u16x8*)&obuf[fr][fc + 8];
        int orow = (NSB - 1) * SB + fr;
        if (isbf) {
            *(u16x8*)((unsigned short*)out + orow * D + fc) = h0;
            *(u16x8*)((unsigned short*)out + orow * D + fc + 8) = h1;
        } else {
            float* op = (float*)out + orow * D + fc;
            fx4 f0, f1, f2, f3;
#pragma unroll
            for (int j = 0; j < 4; ++j) {
                f0[j] = bfbits2f(h0[j]);     f1[j] = bfbits2f(h0[4 + j]);
                f2[j] = bfbits2f(h1[j]);     f3[j] = bfbits2f(h1[4 + j]);
            }
            *(fx4*)op = f0; *(fx4*)(op + 4) = f1;
            *(fx4*)(op + 8) = f2; *(fx4*)(op + 12) = f3;
        }
    }
}

extern "C" void kernel_launch(void* const* d_in, const int* in_sizes, int n_in,
                              void* d_out, int out_size, void* d_ws, size_t ws_size,
                              hipStream_t stream) {
    (void)in_sizes; (void)n_in; (void)out_size; (void)ws_size;

    float* w0 = (float*)d_ws;
    int*   flag = (int*)w0;
    float* Xf   = w0 + 16;
    float* Wqf  = Xf   + N * D;
    float* Wkf  = Wqf  + D * D;
    float* vf   = Wkf  + D * D;
    float* wihf = vf   + D;
    float* whhf = wihf + 3 * D * 2 * D;
    float* bihf = whhf + 3 * D * D;
    float* bhhf = bihf + 3 * D;
    float* q    = bhhf + 3 * D;
    float* kT   = q    + N * D;
    float* wihT = kT   + N * D;
    float* gi   = wihT + 3 * D * 2 * D;

    sniff_kernel<<<1, 64, 0, stream>>>((const unsigned short*)d_in[0], flag);

    ConvArgs A;
    A.p[0] = d_in[0]; A.o[0] = Xf;   A.n[0] = N * D;
    A.p[1] = d_in[1]; A.o[1] = Wqf;  A.n[1] = D * D;
    A.p[2] = d_in[2]; A.o[2] = Wkf;  A.n[2] = D * D;
    A.p[3] = d_in[3]; A.o[3] = vf;   A.n[3] = D;
    A.p[4] = d_in[4]; A.o[4] = wihf; A.n[4] = 3 * D * 2 * D;
    A.p[5] = d_in[5]; A.o[5] = whhf; A.n[5] = 3 * D * D;
    A.p[6] = d_in[6]; A.o[6] = bihf; A.n[6] = 3 * D;
    A.p[7] = d_in[7]; A.o[7] = bhhf; A.n[7] = 3 * D;
    dim3 cgrid(128, 8, 1);
    convert_kernel<<<cgrid, 256, 0, stream>>>(A, flag);

    transpose_wih<<<(3 * D * 2 * D) / 256, 256, 0, stream>>>(wihf, wihT);
    qk_kernel<<<2 * N, D, 0, stream>>>(Xf, Wqf, Wkf, q, kT);
    attn_kernel<<<N, 256, 0, stream>>>(q, kT, vf, Xf, wihT, bihf, gi);
    gru_kernel<<<1, 256, 0, stream>>>(gi, whhf, bhhf, d_out, flag);
}